// Round 1
// 2046.664 us; speedup vs baseline: 1.2100x; 1.2100x over previous
//
#include <hip/hip_runtime.h>
#include <hip/hip_bf16.h>

typedef __attribute__((ext_vector_type(8))) short short8;
typedef __attribute__((ext_vector_type(4))) float f32x4;
typedef __hip_bfloat16 bf16;

#define QLEN 512
#define MLEN 512
#define KLEN 1024
#define BSZ  4
#define DM   1024
#define NH   16
#define DH   64
#define DI   4096
#define NL   4
#define KEMB 1408   // 1024 + 256 + 64 + 16 = 1360, padded to 1408 (x32)

// ================= adaptive embedding as GEMM: gather A rows (2048 x KEMB, bf16) =================
__global__ __launch_bounds__(256) void embA_kernel(
    const int* __restrict__ ids,
    const float* __restrict__ e0, const float* __restrict__ e1,
    const float* __restrict__ e2, const float* __restrict__ e3,
    bf16* __restrict__ Aemb)
{
  const int t = blockIdx.x;          // t = q*BSZ + b
  const int q = t >> 2, b = t & 3;
  const int id = ids[b * QLEN + q];
  const float* tab; int d, off, koff;
  if (id < 20000)       { tab = e0; d = 1024; off = 0;      koff = 0; }
  else if (id < 40000)  { tab = e1; d = 256;  off = 20000;  koff = 1024; }
  else if (id < 200000) { tab = e2; d = 64;   off = 40000;  koff = 1280; }
  else                  { tab = e3; d = 16;   off = 200000; koff = 1344; }
  bf16* row = Aemb + (long)t * KEMB;
  const float* tr = tab + (long)(id - off) * d;
  for (int k = threadIdx.x; k < KEMB; k += 256) {
    const int kk = k - koff;
    float v = 0.f;
    if (kk >= 0 && kk < d) v = tr[kk];
    row[k] = __float2bfloat16(v);
  }
}

// ================= concat proj^T: projT[n][k] (1024 x KEMB, bf16), zero-padded =================
__global__ __launch_bounds__(256) void projT_kernel(
    const float* __restrict__ p0, const float* __restrict__ p1,
    const float* __restrict__ p2, const float* __restrict__ p3,
    bf16* __restrict__ out)
{
  __shared__ float t[32][33];
  const int k0 = blockIdx.x * 32, n0 = blockIdx.y * 32;
  const int nx = threadIdx.x & 31, ky = threadIdx.x >> 5;
#pragma unroll
  for (int p = 0; p < 4; ++p) {
    const int k = k0 + ky + p * 8;
    float v = 0.f;
    if (k < 1024)       v = p0[(long)k * 1024 + n0 + nx];
    else if (k < 1280)  v = p1[(long)(k - 1024) * 1024 + n0 + nx];
    else if (k < 1344)  v = p2[(long)(k - 1280) * 1024 + n0 + nx];
    else if (k < 1360)  v = p3[(long)(k - 1344) * 1024 + n0 + nx];
    t[ky + p * 8][nx] = v;
  }
  __syncthreads();
#pragma unroll
  for (int p = 0; p < 4; ++p)
    out[(long)(n0 + ky + p * 8) * KEMB + k0 + nx] = __float2bfloat16(t[nx][ky + p * 8]);
}

// ================= sinusoidal pos emb -> bf16 =================
__global__ __launch_bounds__(256) void posemb_kernel(bf16* __restrict__ pe)
{
  const int j = blockIdx.x;
  const float pos = (float)(KLEN - 1 - j);
  for (int i = threadIdx.x; i < DM / 2; i += 256) {
    const float freq = expf(-9.210340371976184f * ((float)(2 * i) / (float)DM));
    const float ang = pos * freq;
    pe[(long)j * DM + i]          = __float2bfloat16(sinf(ang));
    pe[(long)j * DM + DM / 2 + i] = __float2bfloat16(cosf(ang));
  }
}

// ================= fp32 (R x C) -> bf16 transposed (C x R) =================
__global__ __launch_bounds__(256) void wtrans_kernel(const float* __restrict__ in,
                                                     bf16* __restrict__ out, int R, int C)
{
  __shared__ float t[32][33];
  const int c0 = blockIdx.x * 32, r0 = blockIdx.y * 32;
  const int cx = threadIdx.x & 31, ry = threadIdx.x >> 5;
#pragma unroll
  for (int p = 0; p < 4; ++p)
    t[ry + p * 8][cx] = in[(long)(r0 + ry + p * 8) * C + c0 + cx];
  __syncthreads();
#pragma unroll
  for (int p = 0; p < 4; ++p)
    out[(long)(c0 + ry + p * 8) * R + r0 + cx] = __float2bfloat16(t[cx][ry + p * 8]);
}

// ================= flat fp32 -> bf16 =================
__global__ __launch_bounds__(256) void conv_kernel(const float* __restrict__ in,
                                                   bf16* __restrict__ out, int n4)
{
  const int i = (blockIdx.x * 256 + threadIdx.x) * 4;
  if (i < n4) {
    const float4 v = *(const float4*)(in + i);
    out[i]     = __float2bfloat16(v.x);
    out[i + 1] = __float2bfloat16(v.y);
    out[i + 2] = __float2bfloat16(v.z);
    out[i + 3] = __float2bfloat16(v.w);
  }
}

// ================= bf16 MFMA GEMM:  C = scale*(A @ B^T_supplied + colbias)  =================
// A: M x K row-major (lda), B: N x K row-major (ldb) [i.e. B^T of the math B]
// flags: 1 = bf16 out, 4 = relu
template<int BM, int BN>
__global__ __launch_bounds__(256) void gemm_bf16(
    const bf16* __restrict__ A, long aStr, int lda,
    const bf16* __restrict__ B, long bStr, int ldb,
    void* __restrict__ C, long cStr, int ldc,
    int K, float scale, const float* __restrict__ bias, int biasStr, int flags)
{
  constexpr int RA = BM / 64, RB = BN / 64, FM = BM / 32, FN = BN / 32;
  __shared__ bf16 As[BM * 32];
  __shared__ bf16 Bs[BN * 32];
  A += (long)blockIdx.z * aStr;
  B += (long)blockIdx.z * bStr;
  const int tid = threadIdx.x, lane = tid & 63;
  const int w = tid >> 6, wr = w >> 1, wc = w & 1;
  const int m0 = blockIdx.y * BM, n0 = blockIdx.x * BN;
  const int l15 = lane & 15, l4 = lane >> 4;
  f32x4 acc[FM][FN] = {};
  for (int k0 = 0; k0 < K; k0 += 32) {
    short8 ra[RA], rb[RB];
#pragma unroll
    for (int r = 0; r < RA; ++r) {
      const int o = r * 4096 + tid * 16, row = o >> 6, cb = o & 63;
      ra[r] = *(const short8*)(A + (size_t)(m0 + row) * lda + k0 + (cb >> 1));
    }
#pragma unroll
    for (int r = 0; r < RB; ++r) {
      const int o = r * 4096 + tid * 16, row = o >> 6, cb = o & 63;
      rb[r] = *(const short8*)(B + (size_t)(n0 + row) * ldb + k0 + (cb >> 1));
    }
    __syncthreads();
#pragma unroll
    for (int r = 0; r < RA; ++r) {
      const int o = r * 4096 + tid * 16, row = o >> 6, cb = o & 63;
      *(short8*)((char*)As + row * 64 + (cb ^ (((row >> 1) & 3) << 4))) = ra[r];
    }
#pragma unroll
    for (int r = 0; r < RB; ++r) {
      const int o = r * 4096 + tid * 16, row = o >> 6, cb = o & 63;
      *(short8*)((char*)Bs + row * 64 + (cb ^ (((row >> 1) & 3) << 4))) = rb[r];
    }
    __syncthreads();
    short8 af[FM], bfr[FN];
#pragma unroll
    for (int f = 0; f < FM; ++f) {
      const int row = wr * (BM / 2) + f * 16 + l15;
      af[f] = *(const short8*)((char*)As + row * 64 + ((16 * l4) ^ (((row >> 1) & 3) << 4)));
    }
#pragma unroll
    for (int f = 0; f < FN; ++f) {
      const int row = wc * (BN / 2) + f * 16 + l15;
      bfr[f] = *(const short8*)((char*)Bs + row * 64 + ((16 * l4) ^ (((row >> 1) & 3) << 4)));
    }
#pragma unroll
    for (int fm = 0; fm < FM; ++fm)
#pragma unroll
      for (int fn = 0; fn < FN; ++fn)
        acc[fm][fn] = __builtin_amdgcn_mfma_f32_16x16x32_bf16(af[fm], bfr[fn], acc[fm][fn], 0, 0, 0);
  }
  const int outbf = flags & 1, relu = flags & 4;
#pragma unroll
  for (int fm = 0; fm < FM; ++fm) {
#pragma unroll
    for (int fn = 0; fn < FN; ++fn) {
      const int col = n0 + wc * (BN / 2) + fn * 16 + l15;
      const int rw0 = m0 + wr * (BM / 2) + fm * 16 + l4 * 4;
      const float bv = bias ? bias[(size_t)blockIdx.z * biasStr + col] : 0.f;
#pragma unroll
      for (int r = 0; r < 4; ++r) {
        float v = (acc[fm][fn][r] + bv) * scale;
        if (relu) v = fmaxf(v, 0.f);
        const int row = rw0 + r;
        if (outbf) {
          ((bf16*)C + (size_t)blockIdx.z * cStr)[(size_t)row * ldc + col] = __float2bfloat16(v);
        } else {
          ((float*)C + (size_t)blockIdx.z * cStr)[(size_t)row * ldc + col] = v;
        }
      }
    }
  }
}

// ================= per-column score biases: rwb_n . K_j  and  rrb_n . rk_p =================
__global__ __launch_bounds__(256) void acb_kernel(const bf16* __restrict__ wh,
                                                  const float* __restrict__ rwb,
                                                  float* __restrict__ acb)
{
  const int idx = blockIdx.x * 256 + threadIdx.x;  // [b][n][j]
  const int b = idx >> 14, n = (idx >> 10) & 15, j = idx & 1023;
  const bf16* kv = wh + (size_t)j * 12288 + b * 3072 + DM + n * 64;
  const float* wv = rwb + n * 64;
  float s = 0.f;
#pragma unroll
  for (int d = 0; d < 64; ++d) s += wv[d] * __bfloat162float(kv[d]);
  acb[idx] = s;
}

__global__ __launch_bounds__(256) void bcb_kernel(const bf16* __restrict__ rkb,
                                                  const float* __restrict__ rrb,
                                                  float* __restrict__ bcb)
{
  const int idx = blockIdx.x * 256 + threadIdx.x;  // [n][p]
  const int n = idx >> 10, p = idx & 1023;
  const bf16* kv = rkb + (size_t)p * DM + n * 64;
  const float* wv = rrb + n * 64;
  float s = 0.f;
#pragma unroll
  for (int d = 0; d < 64; ++d) s += wv[d] * __bfloat162float(kv[d]);
  bcb[idx] = s;
}

// ================= V transpose: vt[b*16+n][d][j] = wh_v[j][b][n][d] =================
__global__ __launch_bounds__(256) void vt_kernel(const bf16* __restrict__ wh, bf16* __restrict__ vt)
{
  const int bn = blockIdx.y, b = bn >> 4, n = bn & 15;
  const int j0 = blockIdx.x * 64;
  __shared__ bf16 t[64][72];
  const bf16* src = wh + (size_t)b * 3072 + 2048 + n * 64;
  const int tid = threadIdx.x;
#pragma unroll
  for (int r = 0; r < 16; ++r) {
    const int jl = r * 4 + (tid >> 6), d = tid & 63;
    t[jl][d] = src[(size_t)(j0 + jl) * 12288 + d];
  }
  __syncthreads();
  bf16* dst = vt + (size_t)bn * 64 * KLEN;
#pragma unroll
  for (int r = 0; r < 16; ++r) {
    const int d = r * 4 + (tid >> 6), j = tid & 63;
    dst[(size_t)d * KLEN + j0 + j] = t[j][d];
  }
}

// ================= masked softmax: score = AC[i][j] + BD[i][j+511-i], in place -> probs =================
__global__ __launch_bounds__(256) void softmax_kernel(bf16* __restrict__ sc,
                                                      const bf16* __restrict__ bdr)
{
  const int bid = blockIdx.x;             // n*512 + i
  const int i = bid & 511;
  bf16* row = sc + (size_t)bid * KLEN;
  const bf16* brow = bdr + (size_t)bid * KLEN + (511 - i);  // gathered rel-shift
  const int valid = MLEN + i + 1;
  const int tid = threadIdx.x;
  __shared__ float red[256];
  float v[4];
#pragma unroll
  for (int s = 0; s < 4; ++s) {
    const int j = tid + s * 256;
    v[s] = j < valid ? __bfloat162float(row[j]) + __bfloat162float(brow[j]) : -1e30f;
  }
  float m = fmaxf(fmaxf(v[0], v[1]), fmaxf(v[2], v[3]));
  red[tid] = m; __syncthreads();
  for (int off = 128; off; off >>= 1) { if (tid < off) red[tid] = fmaxf(red[tid], red[tid + off]); __syncthreads(); }
  m = red[0]; __syncthreads();
  float e[4], s4 = 0.f;
#pragma unroll
  for (int s = 0; s < 4; ++s) {
    const int j = tid + s * 256;
    e[s] = j < valid ? expf(v[s] - m) : 0.f;
    s4 += e[s];
  }
  red[tid] = s4; __syncthreads();
  for (int off = 128; off; off >>= 1) { if (tid < off) red[tid] += red[tid + off]; __syncthreads(); }
  const float inv = 1.f / red[0];
#pragma unroll
  for (int s = 0; s < 4; ++s) row[tid + s * 256] = __float2bfloat16(e[s] * inv);
}

// ================= h = LayerNorm(h + x), dual write fp32 h + bf16 cat(upper) =================
__global__ __launch_bounds__(256) void add_ln_kernel(
    float* __restrict__ h, const float* __restrict__ x,
    const float* __restrict__ g, const float* __restrict__ bb, bf16* __restrict__ cat)
{
  float* hr = h + (long)blockIdx.x * DM;
  const float* xr = x + (long)blockIdx.x * DM;
  bf16* cr = cat + (long)(2048 + blockIdx.x) * DM;
  const int tid = threadIdx.x;
  __shared__ float red[256];
  float v0 = hr[tid] + xr[tid];
  float v1 = hr[tid + 256] + xr[tid + 256];
  float v2 = hr[tid + 512] + xr[tid + 512];
  float v3 = hr[tid + 768] + xr[tid + 768];
  red[tid] = v0 + v1 + v2 + v3; __syncthreads();
  for (int off = 128; off; off >>= 1) { if (tid < off) red[tid] += red[tid + off]; __syncthreads(); }
  const float mean = red[0] * (1.f / DM); __syncthreads();
  const float d0 = v0 - mean, d1 = v1 - mean, d2 = v2 - mean, d3 = v3 - mean;
  red[tid] = d0 * d0 + d1 * d1 + d2 * d2 + d3 * d3; __syncthreads();
  for (int off = 128; off; off >>= 1) { if (tid < off) red[tid] += red[tid + off]; __syncthreads(); }
  const float inv = rsqrtf(red[0] * (1.f / DM) + 1e-5f);
  const float o0 = d0 * inv * g[tid]       + bb[tid];
  const float o1 = d1 * inv * g[tid + 256] + bb[tid + 256];
  const float o2 = d2 * inv * g[tid + 512] + bb[tid + 512];
  const float o3 = d3 * inv * g[tid + 768] + bb[tid + 768];
  hr[tid]       = o0;  cr[tid]       = __float2bfloat16(o0);
  hr[tid + 256] = o1;  cr[tid + 256] = __float2bfloat16(o1);
  hr[tid + 512] = o2;  cr[tid + 512] = __float2bfloat16(o2);
  hr[tid + 768] = o3;  cr[tid + 768] = __float2bfloat16(o3);
}

// ================= (q,b,d) -> (b,q,d) =================
__global__ __launch_bounds__(256) void out_kernel(const float* __restrict__ h, float* __restrict__ out)
{
  const int t = blockIdx.x, q = t >> 2, b = t & 3;
  const float* hr = h + (long)t * DM;
  float* orow = out + ((long)b * QLEN + q) * DM;
  for (int s = 0; s < 4; ++s) orow[threadIdx.x + 256 * s] = hr[threadIdx.x + 256 * s];
}

extern "C" void kernel_launch(void* const* d_in, const int* in_sizes, int n_in,
                              void* d_out, int out_size, void* d_ws, size_t ws_size,
                              hipStream_t stream)
{
  const int*   ids  = (const int*)d_in[0];
  const float* mems = (const float*)d_in[1];
  const float* e0 = (const float*)d_in[2]; const float* p0 = (const float*)d_in[3];
  const float* e1 = (const float*)d_in[4]; const float* p1 = (const float*)d_in[5];
  const float* e2 = (const float*)d_in[6]; const float* p2 = (const float*)d_in[7];
  const float* e3 = (const float*)d_in[8]; const float* p3 = (const float*)d_in[9];
  const float* qkvw = (const float*)d_in[10];
  const float* rnet = (const float*)d_in[11];
  const float* ow   = (const float*)d_in[12];
  const float* rwb  = (const float*)d_in[13];
  const float* rrb  = (const float*)d_in[14];
  const float* ln1g = (const float*)d_in[15];
  const float* ln1b = (const float*)d_in[16];
  const float* fw1  = (const float*)d_in[17];
  const float* fb1  = (const float*)d_in[18];
  const float* fw2  = (const float*)d_in[19];
  const float* fb2  = (const float*)d_in[20];
  const float* ln2g = (const float*)d_in[21];
  const float* ln2b = (const float*)d_in[22];
  float* out = (float*)d_out;

  // -------- workspace layout (bytes), total ~106 MB --------
  char* p = (char*)d_ws;
  float* h    = (float*)p;            p += (size_t)2048 * 1024 * 4;
  bf16*  cat  = (bf16*)p;             p += (size_t)4096 * 1024 * 2;
  bf16*  pe   = (bf16*)p;             p += (size_t)1024 * 1024 * 2;
  bf16*  rkb  = (bf16*)p;             p += (size_t)1024 * 1024 * 2;
  bf16*  wh   = (bf16*)p;             p += (size_t)4096 * 3072 * 2;
  bf16*  vt   = (bf16*)p;             p += (size_t)64 * 64 * 1024 * 2;
  bf16*  qkvT = (bf16*)p;             p += (size_t)3072 * 1024 * 2;
  bf16*  rnT  = (bf16*)p;             p += (size_t)1024 * 1024 * 2;
  bf16*  oT   = (bf16*)p;             p += (size_t)1024 * 1024 * 2;
  // 16 MB region, time-shared:
  //   embed phase:      Aemb (2048 x 1408 bf16, 5.77 MB) + projT (1024 x 1408 bf16, 2.89 MB)
  //   attention phase:  bdr  (16 x 512 x 1024 bf16, 16 MB)  [BD raw scores, per batch]
  //   FFN phase:        f1T (8 MB) + f2T (8 MB)
  bf16*  f1T  = (bf16*)p;
  bf16*  f2T  = (bf16*)(p + (size_t)4096 * 1024 * 2);
  bf16*  bdr  = (bf16*)p;
  bf16*  Aemb = (bf16*)p;
  bf16*  projT= (bf16*)(p + (size_t)2048 * KEMB * 2);
  p += (size_t)8192 * 1024 * 2;
  bf16*  sc   = (bf16*)p;             // 16*512*1024 bf16, unioned with mid
  bf16*  mid  = (bf16*)p;             p += (size_t)16 * 512 * 1024 * 2;
  bf16*  av   = (bf16*)p;             p += (size_t)2048 * 1024 * 2;
  float* tmp  = (float*)p;            p += (size_t)2048 * 1024 * 4;
  float* acb  = (float*)p;            p += (size_t)4 * 16 * 1024 * 4;
  float* bcb  = (float*)p;            p += (size_t)16 * 1024 * 4;

  // -------- adaptive embedding as one MFMA GEMM --------
  embA_kernel<<<2048, 256, 0, stream>>>(ids, e0, e1, e2, e3, Aemb);
  projT_kernel<<<dim3(KEMB / 32, 32), 256, 0, stream>>>(p0, p1, p2, p3, projT);
  gemm_bf16<128, 128><<<dim3(8, 16, 1), 256, 0, stream>>>(
      Aemb, 0, KEMB, projT, 0, KEMB, h, 0, 1024, KEMB, 32.f, nullptr, 0, 0);
  conv_kernel<<<2048, 256, 0, stream>>>(h, cat + (size_t)2048 * 1024, 2048 * 1024);
  posemb_kernel<<<1024, 256, 0, stream>>>(pe);

  for (int l = 0; l < NL; ++l) {
    // weight transposes needed for the attention phase (fp32 -> bf16, B^T layout)
    wtrans_kernel<<<dim3(96, 32), 256, 0, stream>>>(qkvw + (size_t)l * DM * 3072, qkvT, DM, 3072);
    wtrans_kernel<<<dim3(32, 32), 256, 0, stream>>>(rnet + (size_t)l * DM * DM, rnT, DM, DM);
    wtrans_kernel<<<dim3(32, 32), 256, 0, stream>>>(ow   + (size_t)l * DM * DM, oT, DM, DM);
    // mems[l] -> cat lower rows (bf16)
    conv_kernel<<<2048, 256, 0, stream>>>(mems + (size_t)l * 2048 * 1024, cat, 2048 * 1024);

    // w_heads = cat @ qkv_w  -> wh (bf16, 4096 x 3072)
    gemm_bf16<128, 128><<<dim3(24, 32, 1), 256, 0, stream>>>(
        cat, 0, 1024, qkvT, 0, 1024, wh, 0, 3072, 1024, 1.f, nullptr, 0, 1);
    // rk = pos_emb @ r_net_w -> rkb (bf16, 1024 x 1024)
    gemm_bf16<128, 128><<<dim3(8, 8, 1), 256, 0, stream>>>(
        pe, 0, 1024, rnT, 0, 1024, rkb, 0, 1024, 1024, 1.f, nullptr, 0, 1);

    vt_kernel<<<dim3(16, 64), 256, 0, stream>>>(wh, vt);
    acb_kernel<<<256, 256, 0, stream>>>(wh, rwb + l * NH * DH, acb);
    bcb_kernel<<<64, 256, 0, stream>>>(rkb, rrb + l * NH * DH, bcb);

    for (int b = 0; b < BSZ; ++b) {
      const bf16* Aq = wh + (size_t)(2048 + b) * 3072;           // Q rows, lda 12288
      // AC: sc = 0.125*(Q.K^T + rwb.K^T)
      gemm_bf16<128, 128><<<dim3(8, 4, 16), 256, 0, stream>>>(
          Aq, 64, 12288, wh + (size_t)b * 3072 + DM, 64, 12288,
          sc, (long)512 * 1024, 1024, 64, 0.125f, acb + (size_t)b * 16 * 1024, 1024, 1);
      // BD raw: bdr = 0.125*(Q.rk^T + rrb.rk^T)  (plain coalesced write; shift applied in softmax)
      gemm_bf16<128, 128><<<dim3(8, 4, 16), 256, 0, stream>>>(
          Aq, 64, 12288, rkb, 64, 1024,
          bdr, (long)512 * 1024, 1024, 64, 0.125f, bcb, 1024, 1);
      softmax_kernel<<<NH * QLEN, 256, 0, stream>>>(sc, bdr);
      // attn_vec = probs @ V  (B supplied as V^T)
      gemm_bf16<64, 64><<<dim3(1, 8, 16), 256, 0, stream>>>(
          sc, (long)512 * 1024, 1024, vt + (size_t)b * 16 * 64 * 1024, (long)64 * 1024, 1024,
          av + (size_t)b * 1024, 64, 4096, 1024, 1.f, nullptr, 0, 1);
    }

    // attn_out = av @ o_w -> tmp (fp32)
    gemm_bf16<128, 128><<<dim3(8, 16, 1), 256, 0, stream>>>(
        av, 0, 1024, oT, 0, 1024, tmp, 0, 1024, 1024, 1.f, nullptr, 0, 0);
    add_ln_kernel<<<2048, 256, 0, stream>>>(h, tmp, ln1g + l * DM, ln1b + l * DM, cat);

    // FFN weight transposes (deferred: region was bdr during attention)
    wtrans_kernel<<<dim3(128, 32), 256, 0, stream>>>(fw1 + (size_t)l * DM * DI, f1T, DM, DI);
    wtrans_kernel<<<dim3(32, 128), 256, 0, stream>>>(fw2 + (size_t)l * DI * DM, f2T, DI, DM);

    // FFN
    gemm_bf16<128, 128><<<dim3(32, 16, 1), 256, 0, stream>>>(
        cat + (size_t)2048 * 1024, 0, 1024, f1T, 0, 1024, mid, 0, 4096,
        1024, 1.f, fb1 + (size_t)l * DI, 0, 1 | 4);
    gemm_bf16<128, 128><<<dim3(8, 16, 1), 256, 0, stream>>>(
        mid, 0, 4096, f2T, 0, 4096, tmp, 0, 1024, 4096, 1.f, fb2 + (size_t)l * DM, 0, 0);
    add_ln_kernel<<<2048, 256, 0, stream>>>(h, tmp, ln2g + l * DM, ln2b + l * DM, cat);
  }

  out_kernel<<<2048, 256, 0, stream>>>(h, out);
}

// Round 2
// 1752.423 us; speedup vs baseline: 1.4131x; 1.1679x over previous
//
#include <hip/hip_runtime.h>
#include <hip/hip_bf16.h>

typedef __attribute__((ext_vector_type(8))) short short8;
typedef __attribute__((ext_vector_type(4))) float f32x4;
typedef __hip_bfloat16 bf16;

#define QLEN 512
#define MLEN 512
#define KLEN 1024
#define BSZ  4
#define DM   1024
#define NH   16
#define DH   64
#define DI   4096
#define NL   4
#define KEMB 1408   // 1024 + 256 + 64 + 16 = 1360, padded to 1408 (x32)

// ================= adaptive embedding as GEMM: gather A rows (2048 x KEMB, bf16) =================
__global__ __launch_bounds__(256) void embA_kernel(
    const int* __restrict__ ids,
    const float* __restrict__ e0, const float* __restrict__ e1,
    const float* __restrict__ e2, const float* __restrict__ e3,
    bf16* __restrict__ Aemb)
{
  const int t = blockIdx.x;          // t = q*BSZ + b
  const int q = t >> 2, b = t & 3;
  const int id = ids[b * QLEN + q];
  const float* tab; int d, off, koff;
  if (id < 20000)       { tab = e0; d = 1024; off = 0;      koff = 0; }
  else if (id < 40000)  { tab = e1; d = 256;  off = 20000;  koff = 1024; }
  else if (id < 200000) { tab = e2; d = 64;   off = 40000;  koff = 1280; }
  else                  { tab = e3; d = 16;   off = 200000; koff = 1344; }
  bf16* row = Aemb + (long)t * KEMB;
  const float* tr = tab + (long)(id - off) * d;
  for (int k = threadIdx.x; k < KEMB; k += 256) {
    const int kk = k - koff;
    float v = 0.f;
    if (kk >= 0 && kk < d) v = tr[kk];
    row[k] = __float2bfloat16(v);
  }
}

// ================= concat proj^T: projT[n][k] (1024 x KEMB, bf16), zero-padded =================
__global__ __launch_bounds__(256) void projT_kernel(
    const float* __restrict__ p0, const float* __restrict__ p1,
    const float* __restrict__ p2, const float* __restrict__ p3,
    bf16* __restrict__ out)
{
  __shared__ float t[32][33];
  const int k0 = blockIdx.x * 32, n0 = blockIdx.y * 32;
  const int nx = threadIdx.x & 31, ky = threadIdx.x >> 5;
#pragma unroll
  for (int p = 0; p < 4; ++p) {
    const int k = k0 + ky + p * 8;
    float v = 0.f;
    if (k < 1024)       v = p0[(long)k * 1024 + n0 + nx];
    else if (k < 1280)  v = p1[(long)(k - 1024) * 1024 + n0 + nx];
    else if (k < 1344)  v = p2[(long)(k - 1280) * 1024 + n0 + nx];
    else if (k < 1360)  v = p3[(long)(k - 1344) * 1024 + n0 + nx];
    t[ky + p * 8][nx] = v;
  }
  __syncthreads();
#pragma unroll
  for (int p = 0; p < 4; ++p)
    out[(long)(n0 + ky + p * 8) * KEMB + k0 + nx] = __float2bfloat16(t[nx][ky + p * 8]);
}

// ================= sum 2 fp32 partials -> h fp32 + cat bf16 =================
__global__ __launch_bounds__(256) void embsum_kernel(const float* __restrict__ part,
                                                     float* __restrict__ h, bf16* __restrict__ cat)
{
  const long i = ((long)blockIdx.x * 256 + threadIdx.x) * 4;
  const float4 a = *(const float4*)(part + i);
  const float4 b = *(const float4*)(part + 2097152 + i);
  float4 s; s.x = a.x + b.x; s.y = a.y + b.y; s.z = a.z + b.z; s.w = a.w + b.w;
  *(float4*)(h + i) = s;
  bf16* cr = cat + (long)2048 * 1024 + i;
  cr[0] = __float2bfloat16(s.x); cr[1] = __float2bfloat16(s.y);
  cr[2] = __float2bfloat16(s.z); cr[3] = __float2bfloat16(s.w);
}

// ================= sinusoidal pos emb -> bf16 =================
__global__ __launch_bounds__(256) void posemb_kernel(bf16* __restrict__ pe)
{
  const int j = blockIdx.x;
  const float pos = (float)(KLEN - 1 - j);
  for (int i = threadIdx.x; i < DM / 2; i += 256) {
    const float freq = expf(-9.210340371976184f * ((float)(2 * i) / (float)DM));
    const float ang = pos * freq;
    pe[(long)j * DM + i]          = __float2bfloat16(sinf(ang));
    pe[(long)j * DM + DM / 2 + i] = __float2bfloat16(cosf(ang));
  }
}

// ================= fp32 (R x C) -> bf16 transposed (C x R) =================
__global__ __launch_bounds__(256) void wtrans_kernel(const float* __restrict__ in,
                                                     bf16* __restrict__ out, int R, int C)
{
  __shared__ float t[32][33];
  const int c0 = blockIdx.x * 32, r0 = blockIdx.y * 32;
  const int cx = threadIdx.x & 31, ry = threadIdx.x >> 5;
#pragma unroll
  for (int p = 0; p < 4; ++p)
    t[ry + p * 8][cx] = in[(long)(r0 + ry + p * 8) * C + c0 + cx];
  __syncthreads();
#pragma unroll
  for (int p = 0; p < 4; ++p)
    out[(long)(c0 + ry + p * 8) * R + r0 + cx] = __float2bfloat16(t[cx][ry + p * 8]);
}

// ================= flat fp32 -> bf16 =================
__global__ __launch_bounds__(256) void conv_kernel(const float* __restrict__ in,
                                                   bf16* __restrict__ out, int n4)
{
  const int i = (blockIdx.x * 256 + threadIdx.x) * 4;
  if (i < n4) {
    const float4 v = *(const float4*)(in + i);
    out[i]     = __float2bfloat16(v.x);
    out[i + 1] = __float2bfloat16(v.y);
    out[i + 2] = __float2bfloat16(v.z);
    out[i + 3] = __float2bfloat16(v.w);
  }
}

// ================= bf16 MFMA GEMM:  C = scale*(A @ B^T_supplied + colbias)  =================
// A: M x K row-major (lda), B: N x K row-major (ldb) [i.e. B^T of the math B]
// flags: 1 = bf16 out, 4 = relu
// blockIdx.z = zb * zSplit + zc: zb indexes batch/head (aStr/bStr/cStr),
// zc indexes K-chunk (A/B advance zc*K columns, C advances zc*cSplitStr elems).
// bias added only by chunk zc==0.
template<int BM, int BN>
__global__ __launch_bounds__(256) void gemm_bf16(
    const bf16* __restrict__ A, long aStr, int lda,
    const bf16* __restrict__ B, long bStr, int ldb,
    void* __restrict__ C, long cStr, int ldc,
    int K, float scale, const float* __restrict__ bias, int biasStr, int flags,
    int zSplit, long cSplitStr)
{
  constexpr int RA = BM / 64, RB = BN / 64, FM = BM / 32, FN = BN / 32;
  __shared__ bf16 As[BM * 32];
  __shared__ bf16 Bs[BN * 32];
  const int zb = blockIdx.z / zSplit, zc = blockIdx.z % zSplit;
  A += (long)zb * aStr + (long)zc * K;
  B += (long)zb * bStr + (long)zc * K;
  const int tid = threadIdx.x, lane = tid & 63;
  const int w = tid >> 6, wr = w >> 1, wc = w & 1;
  const int m0 = blockIdx.y * BM, n0 = blockIdx.x * BN;
  const int l15 = lane & 15, l4 = lane >> 4;
  f32x4 acc[FM][FN] = {};
  for (int k0 = 0; k0 < K; k0 += 32) {
    short8 ra[RA], rb[RB];
#pragma unroll
    for (int r = 0; r < RA; ++r) {
      const int o = r * 4096 + tid * 16, row = o >> 6, cb = o & 63;
      ra[r] = *(const short8*)(A + (size_t)(m0 + row) * lda + k0 + (cb >> 1));
    }
#pragma unroll
    for (int r = 0; r < RB; ++r) {
      const int o = r * 4096 + tid * 16, row = o >> 6, cb = o & 63;
      rb[r] = *(const short8*)(B + (size_t)(n0 + row) * ldb + k0 + (cb >> 1));
    }
    __syncthreads();
#pragma unroll
    for (int r = 0; r < RA; ++r) {
      const int o = r * 4096 + tid * 16, row = o >> 6, cb = o & 63;
      *(short8*)((char*)As + row * 64 + (cb ^ (((row >> 1) & 3) << 4))) = ra[r];
    }
#pragma unroll
    for (int r = 0; r < RB; ++r) {
      const int o = r * 4096 + tid * 16, row = o >> 6, cb = o & 63;
      *(short8*)((char*)Bs + row * 64 + (cb ^ (((row >> 1) & 3) << 4))) = rb[r];
    }
    __syncthreads();
    short8 af[FM], bfr[FN];
#pragma unroll
    for (int f = 0; f < FM; ++f) {
      const int row = wr * (BM / 2) + f * 16 + l15;
      af[f] = *(const short8*)((char*)As + row * 64 + ((16 * l4) ^ (((row >> 1) & 3) << 4)));
    }
#pragma unroll
    for (int f = 0; f < FN; ++f) {
      const int row = wc * (BN / 2) + f * 16 + l15;
      bfr[f] = *(const short8*)((char*)Bs + row * 64 + ((16 * l4) ^ (((row >> 1) & 3) << 4)));
    }
#pragma unroll
    for (int fm = 0; fm < FM; ++fm)
#pragma unroll
      for (int fn = 0; fn < FN; ++fn)
        acc[fm][fn] = __builtin_amdgcn_mfma_f32_16x16x32_bf16(af[fm], bfr[fn], acc[fm][fn], 0, 0, 0);
  }
  const int outbf = flags & 1, relu = flags & 4;
#pragma unroll
  for (int fm = 0; fm < FM; ++fm) {
#pragma unroll
    for (int fn = 0; fn < FN; ++fn) {
      const int col = n0 + wc * (BN / 2) + fn * 16 + l15;
      const int rw0 = m0 + wr * (BM / 2) + fm * 16 + l4 * 4;
      const float bv = (bias && zc == 0) ? bias[(size_t)zb * biasStr + col] : 0.f;
#pragma unroll
      for (int r = 0; r < 4; ++r) {
        float v = (acc[fm][fn][r] + bv) * scale;
        if (relu) v = fmaxf(v, 0.f);
        const int row = rw0 + r;
        if (outbf) {
          ((bf16*)C + (size_t)zb * cStr + (size_t)zc * cSplitStr)[(size_t)row * ldc + col] = __float2bfloat16(v);
        } else {
          ((float*)C + (size_t)zb * cStr + (size_t)zc * cSplitStr)[(size_t)row * ldc + col] = v;
        }
      }
    }
  }
}

// ================= per-column score biases: rwb_n . K_j  and  rrb_n . rk_p =================
__global__ __launch_bounds__(256) void acb_kernel(const bf16* __restrict__ wh,
                                                  const float* __restrict__ rwb,
                                                  float* __restrict__ acb)
{
  const int idx = blockIdx.x * 256 + threadIdx.x;  // [b][n][j]
  const int b = idx >> 14, n = (idx >> 10) & 15, j = idx & 1023;
  const bf16* kv = wh + (size_t)j * 12288 + b * 3072 + DM + n * 64;
  const float* wv = rwb + n * 64;
  float s = 0.f;
#pragma unroll
  for (int d = 0; d < 64; ++d) s += wv[d] * __bfloat162float(kv[d]);
  acb[idx] = s;
}

__global__ __launch_bounds__(256) void bcb_kernel(const bf16* __restrict__ rkb,
                                                  const float* __restrict__ rrb,
                                                  float* __restrict__ bcb)
{
  const int idx = blockIdx.x * 256 + threadIdx.x;  // [n][p]
  const int n = idx >> 10, p = idx & 1023;
  const bf16* kv = rkb + (size_t)p * DM + n * 64;
  const float* wv = rrb + n * 64;
  float s = 0.f;
#pragma unroll
  for (int d = 0; d < 64; ++d) s += wv[d] * __bfloat162float(kv[d]);
  bcb[idx] = s;
}

// ================= V transpose: vt[b*16+n][d][j] = wh_v[j][b][n][d] =================
__global__ __launch_bounds__(256) void vt_kernel(const bf16* __restrict__ wh, bf16* __restrict__ vt)
{
  const int bn = blockIdx.y, b = bn >> 4, n = bn & 15;
  const int j0 = blockIdx.x * 64;
  __shared__ bf16 t[64][72];
  const bf16* src = wh + (size_t)b * 3072 + 2048 + n * 64;
  const int tid = threadIdx.x;
#pragma unroll
  for (int r = 0; r < 16; ++r) {
    const int jl = r * 4 + (tid >> 6), d = tid & 63;
    t[jl][d] = src[(size_t)(j0 + jl) * 12288 + d];
  }
  __syncthreads();
  bf16* dst = vt + (size_t)bn * 64 * KLEN;
#pragma unroll
  for (int r = 0; r < 16; ++r) {
    const int d = r * 4 + (tid >> 6), j = tid & 63;
    dst[(size_t)d * KLEN + j0 + j] = t[j][d];
  }
}

// ================= masked softmax: score = AC[i][j] + BD[i][j+511-i], in place -> probs =================
__global__ __launch_bounds__(256) void softmax_kernel(bf16* __restrict__ sc,
                                                      const bf16* __restrict__ bdr)
{
  const int bid = blockIdx.x;             // n*512 + i
  const int i = bid & 511;
  bf16* row = sc + (size_t)bid * KLEN;
  const bf16* brow = bdr + (size_t)bid * KLEN + (511 - i);  // gathered rel-shift
  const int valid = MLEN + i + 1;
  const int tid = threadIdx.x;
  __shared__ float red[256];
  float v[4];
#pragma unroll
  for (int s = 0; s < 4; ++s) {
    const int j = tid + s * 256;
    v[s] = j < valid ? __bfloat162float(row[j]) + __bfloat162float(brow[j]) : -1e30f;
  }
  float m = fmaxf(fmaxf(v[0], v[1]), fmaxf(v[2], v[3]));
  red[tid] = m; __syncthreads();
  for (int off = 128; off; off >>= 1) { if (tid < off) red[tid] = fmaxf(red[tid], red[tid + off]); __syncthreads(); }
  m = red[0]; __syncthreads();
  float e[4], s4 = 0.f;
#pragma unroll
  for (int s = 0; s < 4; ++s) {
    const int j = tid + s * 256;
    e[s] = j < valid ? expf(v[s] - m) : 0.f;
    s4 += e[s];
  }
  red[tid] = s4; __syncthreads();
  for (int off = 128; off; off >>= 1) { if (tid < off) red[tid] += red[tid + off]; __syncthreads(); }
  const float inv = 1.f / red[0];
#pragma unroll
  for (int s = 0; s < 4; ++s) row[tid + s * 256] = __float2bfloat16(e[s] * inv);
}

// ================= PV split-K reduce: av_b = bf16(t0 + t1) =================
__global__ __launch_bounds__(256) void pvred_kernel(const float* __restrict__ t, bf16* __restrict__ av_b)
{
  const int i = (blockIdx.x * 256 + threadIdx.x) * 4;   // over 512*1024
  const int row = i >> 10, c = i & 1023;
  const float4 a = *(const float4*)(t + i);
  const float4 b = *(const float4*)(t + 512 * 1024 + i);
  bf16* dst = av_b + (size_t)row * 4096 + c;
  dst[0] = __float2bfloat16(a.x + b.x);
  dst[1] = __float2bfloat16(a.y + b.y);
  dst[2] = __float2bfloat16(a.z + b.z);
  dst[3] = __float2bfloat16(a.w + b.w);
}

// ================= h = LayerNorm(h + x0 [+x1+x2+x3]), dual write fp32 h + bf16 cat(upper) =================
__global__ __launch_bounds__(256) void add_ln_kernel(
    float* __restrict__ h,
    const float* __restrict__ x0, const float* __restrict__ x1,
    const float* __restrict__ x2, const float* __restrict__ x3,
    const float* __restrict__ g, const float* __restrict__ bb, bf16* __restrict__ cat)
{
  float* hr = h + (long)blockIdx.x * DM;
  const long o = (long)blockIdx.x * DM;
  bf16* cr = cat + (long)(2048 + blockIdx.x) * DM;
  const int tid = threadIdx.x;
  __shared__ float red[256];
  float v0 = hr[tid], v1 = hr[tid + 256], v2 = hr[tid + 512], v3 = hr[tid + 768];
  v0 += x0[o + tid]; v1 += x0[o + tid + 256]; v2 += x0[o + tid + 512]; v3 += x0[o + tid + 768];
  if (x1) { v0 += x1[o + tid]; v1 += x1[o + tid + 256]; v2 += x1[o + tid + 512]; v3 += x1[o + tid + 768]; }
  if (x2) { v0 += x2[o + tid]; v1 += x2[o + tid + 256]; v2 += x2[o + tid + 512]; v3 += x2[o + tid + 768]; }
  if (x3) { v0 += x3[o + tid]; v1 += x3[o + tid + 256]; v2 += x3[o + tid + 512]; v3 += x3[o + tid + 768]; }
  red[tid] = v0 + v1 + v2 + v3; __syncthreads();
  for (int off = 128; off; off >>= 1) { if (tid < off) red[tid] += red[tid + off]; __syncthreads(); }
  const float mean = red[0] * (1.f / DM); __syncthreads();
  const float d0 = v0 - mean, d1 = v1 - mean, d2 = v2 - mean, d3 = v3 - mean;
  red[tid] = d0 * d0 + d1 * d1 + d2 * d2 + d3 * d3; __syncthreads();
  for (int off = 128; off; off >>= 1) { if (tid < off) red[tid] += red[tid + off]; __syncthreads(); }
  const float inv = rsqrtf(red[0] * (1.f / DM) + 1e-5f);
  const float o0 = d0 * inv * g[tid]       + bb[tid];
  const float o1 = d1 * inv * g[tid + 256] + bb[tid + 256];
  const float o2 = d2 * inv * g[tid + 512] + bb[tid + 512];
  const float o3 = d3 * inv * g[tid + 768] + bb[tid + 768];
  hr[tid]       = o0;  cr[tid]       = __float2bfloat16(o0);
  hr[tid + 256] = o1;  cr[tid + 256] = __float2bfloat16(o1);
  hr[tid + 512] = o2;  cr[tid + 512] = __float2bfloat16(o2);
  hr[tid + 768] = o3;  cr[tid + 768] = __float2bfloat16(o3);
}

// ================= (q,b,d) -> (b,q,d) =================
__global__ __launch_bounds__(256) void out_kernel(const float* __restrict__ h, float* __restrict__ out)
{
  const int t = blockIdx.x, q = t >> 2, b = t & 3;
  const float* hr = h + (long)t * DM;
  float* orow = out + ((long)b * QLEN + q) * DM;
  for (int s = 0; s < 4; ++s) orow[threadIdx.x + 256 * s] = hr[threadIdx.x + 256 * s];
}

extern "C" void kernel_launch(void* const* d_in, const int* in_sizes, int n_in,
                              void* d_out, int out_size, void* d_ws, size_t ws_size,
                              hipStream_t stream)
{
  const int*   ids  = (const int*)d_in[0];
  const float* mems = (const float*)d_in[1];
  const float* e0 = (const float*)d_in[2]; const float* p0 = (const float*)d_in[3];
  const float* e1 = (const float*)d_in[4]; const float* p1 = (const float*)d_in[5];
  const float* e2 = (const float*)d_in[6]; const float* p2 = (const float*)d_in[7];
  const float* e3 = (const float*)d_in[8]; const float* p3 = (const float*)d_in[9];
  const float* qkvw = (const float*)d_in[10];
  const float* rnet = (const float*)d_in[11];
  const float* ow   = (const float*)d_in[12];
  const float* rwb  = (const float*)d_in[13];
  const float* rrb  = (const float*)d_in[14];
  const float* ln1g = (const float*)d_in[15];
  const float* ln1b = (const float*)d_in[16];
  const float* fw1  = (const float*)d_in[17];
  const float* fb1  = (const float*)d_in[18];
  const float* fw2  = (const float*)d_in[19];
  const float* fb2  = (const float*)d_in[20];
  const float* ln2g = (const float*)d_in[21];
  const float* ln2b = (const float*)d_in[22];
  float* out = (float*)d_out;

  // -------- workspace layout (bytes), total ~106 MB --------
  char* p = (char*)d_ws;
  float* h    = (float*)p;            p += (size_t)2048 * 1024 * 4;
  bf16*  cat  = (bf16*)p;             p += (size_t)4096 * 1024 * 2;
  bf16*  pe   = (bf16*)p;             p += (size_t)1024 * 1024 * 2;
  bf16*  rkb  = (bf16*)p;             p += (size_t)1024 * 1024 * 2;
  bf16*  wh   = (bf16*)p;             p += (size_t)4096 * 3072 * 2;
  bf16*  vt   = (bf16*)p;             p += (size_t)64 * 64 * 1024 * 2;
  bf16*  qkvT = (bf16*)p;             p += (size_t)3072 * 1024 * 2;
  bf16*  rnT  = (bf16*)p;             p += (size_t)1024 * 1024 * 2;
  bf16*  oT   = (bf16*)p;             p += (size_t)1024 * 1024 * 2;
  // 16 MB region A, time-shared:
  //   embed phase:      Aemb (2048 x KEMB bf16) + projT (1024 x KEMB bf16)
  //   attention phase:  bdr (16 MB)   [BD raw scores, per batch]
  //   post-attn:        proj split-K partials (16 MB fp32)
  //   FFN phase:        f1T (8 MB) + f2T (8 MB); f1T half doubles as ffn2 partial0
  bf16*  f1T  = (bf16*)p;
  bf16*  f2T  = (bf16*)(p + (size_t)4096 * 1024 * 2);
  bf16*  bdr  = (bf16*)p;
  bf16*  Aemb = (bf16*)p;
  bf16*  projT= (bf16*)(p + (size_t)2048 * KEMB * 2);
  float* partP= (float*)p;            // proj partials: 2 x (2048x1024 fp32)
  p += (size_t)8192 * 1024 * 2;
  // 16 MB region B, time-shared: sc/mid union + embed partials
  bf16*  sc   = (bf16*)p;
  bf16*  mid  = (bf16*)p;
  float* partE= (float*)p;            // embed partials: 2 x (2048x1024 fp32)
  p += (size_t)16 * 512 * 1024 * 2;
  bf16*  av   = (bf16*)p;             p += (size_t)2048 * 1024 * 2;
  float* tmp  = (float*)p;            p += (size_t)2048 * 1024 * 4;
  float* acb  = (float*)p;            p += (size_t)4 * 16 * 1024 * 4;
  float* bcb  = (float*)p;            p += (size_t)16 * 1024 * 4;

  // -------- adaptive embedding as one MFMA GEMM (split-K x2 for occupancy) --------
  embA_kernel<<<2048, 256, 0, stream>>>(ids, e0, e1, e2, e3, Aemb);
  projT_kernel<<<dim3(KEMB / 32, 32), 256, 0, stream>>>(p0, p1, p2, p3, projT);
  gemm_bf16<128, 64><<<dim3(16, 16, 2), 256, 0, stream>>>(
      Aemb, 0, KEMB, projT, 0, KEMB, partE, 0, 1024, KEMB / 2, 32.f, nullptr, 0, 0,
      2, 2097152);
  embsum_kernel<<<2048, 256, 0, stream>>>(partE, h, cat);
  posemb_kernel<<<1024, 256, 0, stream>>>(pe);

  for (int l = 0; l < NL; ++l) {
    // weight transposes needed for the attention phase (fp32 -> bf16, B^T layout)
    wtrans_kernel<<<dim3(96, 32), 256, 0, stream>>>(qkvw + (size_t)l * DM * 3072, qkvT, DM, 3072);
    wtrans_kernel<<<dim3(32, 32), 256, 0, stream>>>(rnet + (size_t)l * DM * DM, rnT, DM, DM);
    wtrans_kernel<<<dim3(32, 32), 256, 0, stream>>>(ow   + (size_t)l * DM * DM, oT, DM, DM);
    // mems[l] -> cat lower rows (bf16)
    conv_kernel<<<2048, 256, 0, stream>>>(mems + (size_t)l * 2048 * 1024, cat, 2048 * 1024);

    // w_heads = cat @ qkv_w  -> wh (bf16, 4096 x 3072)
    gemm_bf16<128, 128><<<dim3(24, 32, 1), 256, 0, stream>>>(
        cat, 0, 1024, qkvT, 0, 1024, wh, 0, 3072, 1024, 1.f, nullptr, 0, 1, 1, 0);
    // rk = pos_emb @ r_net_w -> rkb (bf16, 1024 x 1024)
    gemm_bf16<128, 128><<<dim3(8, 8, 1), 256, 0, stream>>>(
        pe, 0, 1024, rnT, 0, 1024, rkb, 0, 1024, 1024, 1.f, nullptr, 0, 1, 1, 0);

    vt_kernel<<<dim3(16, 64), 256, 0, stream>>>(wh, vt);
    acb_kernel<<<256, 256, 0, stream>>>(wh, rwb + l * NH * DH, acb);
    bcb_kernel<<<64, 256, 0, stream>>>(rkb, rrb + l * NH * DH, bcb);

    for (int b = 0; b < BSZ; ++b) {
      const bf16* Aq = wh + (size_t)(2048 + b) * 3072;           // Q rows, lda 12288
      // AC: sc = 0.125*(Q.K^T + rwb.K^T)
      gemm_bf16<128, 128><<<dim3(8, 4, 16), 256, 0, stream>>>(
          Aq, 64, 12288, wh + (size_t)b * 3072 + DM, 64, 12288,
          sc, (long)512 * 1024, 1024, 64, 0.125f, acb + (size_t)b * 16 * 1024, 1024, 1, 1, 0);
      // BD raw: bdr = 0.125*(Q.rk^T + rrb.rk^T)  (plain write; shift applied in softmax)
      gemm_bf16<128, 128><<<dim3(8, 4, 16), 256, 0, stream>>>(
          Aq, 64, 12288, rkb, 64, 1024,
          bdr, (long)512 * 1024, 1024, 64, 0.125f, bcb, 1024, 1, 1, 0);
      softmax_kernel<<<NH * QLEN, 256, 0, stream>>>(sc, bdr);
      // attn_vec = probs @ V  (B supplied as V^T), split-K x2 -> fp32 partials in tmp
      gemm_bf16<64, 64><<<dim3(1, 8, 32), 256, 0, stream>>>(
          sc, (long)512 * 1024, 1024, vt + (size_t)b * 16 * 64 * 1024, (long)64 * 1024, 1024,
          tmp, 64, 1024, 512, 1.f, nullptr, 0, 0, 2, (long)512 * 1024);
      pvred_kernel<<<512, 256, 0, stream>>>(tmp, av + (size_t)b * 1024);
    }

    // attn_out = av @ o_w (split-K x2, fp32 partials), summed in add_ln
    gemm_bf16<128, 64><<<dim3(16, 16, 2), 256, 0, stream>>>(
        av, 0, 1024, oT, 0, 1024, partP, 0, 1024, 512, 1.f, nullptr, 0, 0,
        2, 2097152);
    add_ln_kernel<<<2048, 256, 0, stream>>>(h, partP, partP + 2097152, nullptr, nullptr,
                                            ln1g + l * DM, ln1b + l * DM, cat);

    // FFN weight transposes (deferred: region was bdr/partials during attention)
    wtrans_kernel<<<dim3(128, 32), 256, 0, stream>>>(fw1 + (size_t)l * DM * DI, f1T, DM, DI);
    wtrans_kernel<<<dim3(32, 128), 256, 0, stream>>>(fw2 + (size_t)l * DI * DM, f2T, DI, DM);

    // FFN
    gemm_bf16<128, 128><<<dim3(32, 16, 1), 256, 0, stream>>>(
        cat + (size_t)2048 * 1024, 0, 1024, f1T, 0, 1024, mid, 0, 4096,
        1024, 1.f, fb1 + (size_t)l * DI, 0, 1 | 4, 1, 0);
    // ffn2 split-K x2: partial0 -> f1T region (dead after ffn1), partial1 -> tmp
    {
      float* f2p0 = (float*)f1T;
      const long csplit2 = (long)(tmp - f2p0);
      gemm_bf16<128, 64><<<dim3(16, 16, 2), 256, 0, stream>>>(
          mid, 0, 4096, f2T, 0, 4096, f2p0, 0, 1024, 2048, 1.f, fb2 + (size_t)l * DM, 0, 0,
          2, csplit2);
      add_ln_kernel<<<2048, 256, 0, stream>>>(h, f2p0, tmp, nullptr, nullptr,
                                              ln2g + l * DM, ln2b + l * DM, cat);
    }
  }

  out_kernel<<<2048, 256, 0, stream>>>(h, out);
}

// Round 3
// 1419.828 us; speedup vs baseline: 1.7442x; 1.2343x over previous
//
#include <hip/hip_runtime.h>
#include <hip/hip_bf16.h>

typedef __attribute__((ext_vector_type(8))) short short8;
typedef __attribute__((ext_vector_type(4))) float f32x4;
typedef __hip_bfloat16 bf16;

#define QLEN 512
#define MLEN 512
#define KLEN 1024
#define BSZ  4
#define DM   1024
#define NH   16
#define DH   64
#define DI   4096
#define NL   4
#define KEMB 1408   // 1024 + 256 + 64 + 16 = 1360, padded to 1408 (x32)

// ================= adaptive embedding as GEMM: gather A rows (2048 x KEMB, bf16) =================
__global__ __launch_bounds__(256) void embA_kernel(
    const int* __restrict__ ids,
    const float* __restrict__ e0, const float* __restrict__ e1,
    const float* __restrict__ e2, const float* __restrict__ e3,
    bf16* __restrict__ Aemb)
{
  const int t = blockIdx.x;          // t = q*BSZ + b
  const int q = t >> 2, b = t & 3;
  const int id = ids[b * QLEN + q];
  const float* tab; int d, off, koff;
  if (id < 20000)       { tab = e0; d = 1024; off = 0;      koff = 0; }
  else if (id < 40000)  { tab = e1; d = 256;  off = 20000;  koff = 1024; }
  else if (id < 200000) { tab = e2; d = 64;   off = 40000;  koff = 1280; }
  else                  { tab = e3; d = 16;   off = 200000; koff = 1344; }
  bf16* row = Aemb + (long)t * KEMB;
  const float* tr = tab + (long)(id - off) * d;
  for (int k = threadIdx.x; k < KEMB; k += 256) {
    const int kk = k - koff;
    float v = 0.f;
    if (kk >= 0 && kk < d) v = tr[kk];
    row[k] = __float2bfloat16(v);
  }
}

// ================= concat proj^T: projT[n][k] (1024 x KEMB, bf16), zero-padded =================
__global__ __launch_bounds__(256) void projT_kernel(
    const float* __restrict__ p0, const float* __restrict__ p1,
    const float* __restrict__ p2, const float* __restrict__ p3,
    bf16* __restrict__ out)
{
  __shared__ float t[32][33];
  const int k0 = blockIdx.x * 32, n0 = blockIdx.y * 32;
  const int nx = threadIdx.x & 31, ky = threadIdx.x >> 5;
#pragma unroll
  for (int p = 0; p < 4; ++p) {
    const int k = k0 + ky + p * 8;
    float v = 0.f;
    if (k < 1024)       v = p0[(long)k * 1024 + n0 + nx];
    else if (k < 1280)  v = p1[(long)(k - 1024) * 1024 + n0 + nx];
    else if (k < 1344)  v = p2[(long)(k - 1280) * 1024 + n0 + nx];
    else if (k < 1360)  v = p3[(long)(k - 1344) * 1024 + n0 + nx];
    t[ky + p * 8][nx] = v;
  }
  __syncthreads();
#pragma unroll
  for (int p = 0; p < 4; ++p)
    out[(long)(n0 + ky + p * 8) * KEMB + k0 + nx] = __float2bfloat16(t[nx][ky + p * 8]);
}

// ================= sum 2 fp32 partials -> h fp32 + cat bf16 (upper) =================
__global__ __launch_bounds__(256) void embsum_kernel(const float* __restrict__ part,
                                                     float* __restrict__ h, bf16* __restrict__ cat)
{
  const long i = ((long)blockIdx.x * 256 + threadIdx.x) * 4;
  const float4 a = *(const float4*)(part + i);
  const float4 b = *(const float4*)(part + 2097152 + i);
  float4 s; s.x = a.x + b.x; s.y = a.y + b.y; s.z = a.z + b.z; s.w = a.w + b.w;
  *(float4*)(h + i) = s;
  bf16* cr = cat + (long)2048 * 1024 + i;
  cr[0] = __float2bfloat16(s.x); cr[1] = __float2bfloat16(s.y);
  cr[2] = __float2bfloat16(s.z); cr[3] = __float2bfloat16(s.w);
}

// ================= sinusoidal pos emb -> bf16 =================
__global__ __launch_bounds__(256) void posemb_kernel(bf16* __restrict__ pe)
{
  const int j = blockIdx.x;
  const float pos = (float)(KLEN - 1 - j);
  for (int i = threadIdx.x; i < DM / 2; i += 256) {
    const float freq = expf(-9.210340371976184f * ((float)(2 * i) / (float)DM));
    const float ang = pos * freq;
    pe[(long)j * DM + i]          = __float2bfloat16(sinf(ang));
    pe[(long)j * DM + DM / 2 + i] = __float2bfloat16(cosf(ang));
  }
}

// ================= fp32 (R x C) -> bf16 transposed (C x R), z = layer =================
__global__ __launch_bounds__(256) void wtrans_kernel(const float* __restrict__ in,
                                                     bf16* __restrict__ out, int R, int C)
{
  __shared__ float t[32][33];
  in  += (long)blockIdx.z * R * C;
  out += (long)blockIdx.z * R * C;
  const int c0 = blockIdx.x * 32, r0 = blockIdx.y * 32;
  const int cx = threadIdx.x & 31, ry = threadIdx.x >> 5;
#pragma unroll
  for (int p = 0; p < 4; ++p)
    t[ry + p * 8][cx] = in[(long)(r0 + ry + p * 8) * C + c0 + cx];
  __syncthreads();
#pragma unroll
  for (int p = 0; p < 4; ++p)
    out[(long)(c0 + ry + p * 8) * R + r0 + cx] = __float2bfloat16(t[cx][ry + p * 8]);
}

// ================= all mems (NL x 2048 x 1024 fp32) -> lower halves of cats[l] =================
__global__ __launch_bounds__(256) void memsconv_kernel(const float* __restrict__ mems,
                                                       bf16* __restrict__ cat0)
{
  const long i = ((long)blockIdx.x * 256 + threadIdx.x) * 4;   // over NL*2048*1024
  const long l = i >> 21, rem = i & ((1 << 21) - 1);
  const float4 v = *(const float4*)(mems + i);
  bf16* dst = cat0 + l * 4194304 + rem;
  dst[0] = __float2bfloat16(v.x); dst[1] = __float2bfloat16(v.y);
  dst[2] = __float2bfloat16(v.z); dst[3] = __float2bfloat16(v.w);
}

// ================= bf16 MFMA GEMM:  C = scale*(A @ B^T_supplied + colbias)  =================
// A: M x K row-major (lda), B: N x K row-major (ldb) [i.e. B^T of the math B]
// flags: 1 = bf16 out, 4 = relu
// blockIdx.z = (zb*zN + zn)*zSplit + zc:
//   zb/zn: batch-style offsets via *StrB / *StrN (elements)
//   zc:    K-split chunk; A/B advance zc*K columns, C advances zc*cSplitStr elems;
//          bias added only by chunk zc==0.
template<int BM, int BN>
__global__ __launch_bounds__(256) void gemm_bf16(
    const bf16* __restrict__ A, long aStrB, long aStrN, int lda,
    const bf16* __restrict__ B, long bStrB, long bStrN, int ldb,
    void* __restrict__ C, long cStrB, long cStrN, int ldc,
    int K, float scale, const float* __restrict__ bias, long biasStrB, long biasStrN,
    int flags, int zN, int zSplit, long cSplitStr)
{
  constexpr int RA = BM / 64, RB = BN / 64, FM = BM / 32, FN = BN / 32;
  __shared__ bf16 As[BM * 32];
  __shared__ bf16 Bs[BN * 32];
  const int zc = blockIdx.z % zSplit, zt = blockIdx.z / zSplit;
  const int zn = zt % zN, zb = zt / zN;
  A += (long)zb * aStrB + (long)zn * aStrN + (long)zc * K;
  B += (long)zb * bStrB + (long)zn * bStrN + (long)zc * K;
  const int tid = threadIdx.x, lane = tid & 63;
  const int w = tid >> 6, wr = w >> 1, wc = w & 1;
  const int m0 = blockIdx.y * BM, n0 = blockIdx.x * BN;
  const int l15 = lane & 15, l4 = lane >> 4;
  f32x4 acc[FM][FN] = {};
  for (int k0 = 0; k0 < K; k0 += 32) {
    short8 ra[RA], rb[RB];
#pragma unroll
    for (int r = 0; r < RA; ++r) {
      const int o = r * 4096 + tid * 16, row = o >> 6, cb = o & 63;
      ra[r] = *(const short8*)(A + (size_t)(m0 + row) * lda + k0 + (cb >> 1));
    }
#pragma unroll
    for (int r = 0; r < RB; ++r) {
      const int o = r * 4096 + tid * 16, row = o >> 6, cb = o & 63;
      rb[r] = *(const short8*)(B + (size_t)(n0 + row) * ldb + k0 + (cb >> 1));
    }
    __syncthreads();
#pragma unroll
    for (int r = 0; r < RA; ++r) {
      const int o = r * 4096 + tid * 16, row = o >> 6, cb = o & 63;
      *(short8*)((char*)As + row * 64 + (cb ^ (((row >> 1) & 3) << 4))) = ra[r];
    }
#pragma unroll
    for (int r = 0; r < RB; ++r) {
      const int o = r * 4096 + tid * 16, row = o >> 6, cb = o & 63;
      *(short8*)((char*)Bs + row * 64 + (cb ^ (((row >> 1) & 3) << 4))) = rb[r];
    }
    __syncthreads();
    short8 af[FM], bfr[FN];
#pragma unroll
    for (int f = 0; f < FM; ++f) {
      const int row = wr * (BM / 2) + f * 16 + l15;
      af[f] = *(const short8*)((char*)As + row * 64 + ((16 * l4) ^ (((row >> 1) & 3) << 4)));
    }
#pragma unroll
    for (int f = 0; f < FN; ++f) {
      const int row = wc * (BN / 2) + f * 16 + l15;
      bfr[f] = *(const short8*)((char*)Bs + row * 64 + ((16 * l4) ^ (((row >> 1) & 3) << 4)));
    }
#pragma unroll
    for (int fm = 0; fm < FM; ++fm)
#pragma unroll
      for (int fn = 0; fn < FN; ++fn)
        acc[fm][fn] = __builtin_amdgcn_mfma_f32_16x16x32_bf16(af[fm], bfr[fn], acc[fm][fn], 0, 0, 0);
  }
  const int outbf = flags & 1, relu = flags & 4;
#pragma unroll
  for (int fm = 0; fm < FM; ++fm) {
#pragma unroll
    for (int fn = 0; fn < FN; ++fn) {
      const int col = n0 + wc * (BN / 2) + fn * 16 + l15;
      const int rw0 = m0 + wr * (BM / 2) + fm * 16 + l4 * 4;
      const float bv = (bias && zc == 0) ? bias[(size_t)zb * biasStrB + (size_t)zn * biasStrN + col] : 0.f;
#pragma unroll
      for (int r = 0; r < 4; ++r) {
        float v = (acc[fm][fn][r] + bv) * scale;
        if (relu) v = fmaxf(v, 0.f);
        const int row = rw0 + r;
        const size_t cOff = (size_t)zb * cStrB + (size_t)zn * cStrN + (size_t)zc * cSplitStr;
        if (outbf) {
          ((bf16*)C + cOff)[(size_t)row * ldc + col] = __float2bfloat16(v);
        } else {
          ((float*)C + cOff)[(size_t)row * ldc + col] = v;
        }
      }
    }
  }
}

// ================= per-column score biases: rwb_n . K_j  (per layer) =================
__global__ __launch_bounds__(256) void acb_kernel(const bf16* __restrict__ wh,
                                                  const float* __restrict__ rwb,
                                                  float* __restrict__ acb)
{
  const int idx = blockIdx.x * 256 + threadIdx.x;  // [b][n][j]
  const int b = idx >> 14, n = (idx >> 10) & 15, j = idx & 1023;
  const bf16* kv = wh + (size_t)j * 12288 + b * 3072 + DM + n * 64;
  const float* wv = rwb + n * 64;
  float s = 0.f;
#pragma unroll
  for (int d = 0; d < 64; ++d) s += wv[d] * __bfloat162float(kv[d]);
  acb[idx] = s;
}

// ================= rrb_n . rk_p for ALL layers =================
__global__ __launch_bounds__(256) void bcb_kernel(const bf16* __restrict__ rkb,
                                                  const float* __restrict__ rrb,
                                                  float* __restrict__ bcb)
{
  const int idx = blockIdx.x * 256 + threadIdx.x;  // [l][n][p]
  const int l = idx >> 14, n = (idx >> 10) & 15, p = idx & 1023;
  const bf16* kv = rkb + (size_t)l * 1048576 + (size_t)p * DM + n * 64;
  const float* wv = rrb + l * 1024 + n * 64;
  float s = 0.f;
#pragma unroll
  for (int d = 0; d < 64; ++d) s += wv[d] * __bfloat162float(kv[d]);
  bcb[idx] = s;
}

// ================= V transpose: vt[b*16+n][d][j] = wh_v[j][b][n][d] =================
__global__ __launch_bounds__(256) void vt_kernel(const bf16* __restrict__ wh, bf16* __restrict__ vt)
{
  const int bn = blockIdx.y, b = bn >> 4, n = bn & 15;
  const int j0 = blockIdx.x * 64;
  __shared__ bf16 t[64][72];
  const bf16* src = wh + (size_t)b * 3072 + 2048 + n * 64;
  const int tid = threadIdx.x;
#pragma unroll
  for (int r = 0; r < 16; ++r) {
    const int jl = r * 4 + (tid >> 6), d = tid & 63;
    t[jl][d] = src[(size_t)(j0 + jl) * 12288 + d];
  }
  __syncthreads();
  bf16* dst = vt + (size_t)bn * 64 * KLEN;
#pragma unroll
  for (int r = 0; r < 16; ++r) {
    const int d = r * 4 + (tid >> 6), j = tid & 63;
    dst[(size_t)d * KLEN + j0 + j] = t[j][d];
  }
}

// ================= masked softmax: score = AC[i][j] + BD[i][j+511-i], in place -> probs =================
__global__ __launch_bounds__(256) void softmax_kernel(bf16* __restrict__ sc,
                                                      const bf16* __restrict__ bdr)
{
  const int bid = blockIdx.x;             // ((b*16+n)*512) + i
  const int i = bid & 511;
  bf16* row = sc + (size_t)bid * KLEN;
  const bf16* brow = bdr + (size_t)bid * KLEN + (511 - i);  // gathered rel-shift
  const int valid = MLEN + i + 1;
  const int tid = threadIdx.x;
  __shared__ float red[256];
  float v[4];
#pragma unroll
  for (int s = 0; s < 4; ++s) {
    const int j = tid + s * 256;
    v[s] = j < valid ? __bfloat162float(row[j]) + __bfloat162float(brow[j]) : -1e30f;
  }
  float m = fmaxf(fmaxf(v[0], v[1]), fmaxf(v[2], v[3]));
  red[tid] = m; __syncthreads();
  for (int off = 128; off; off >>= 1) { if (tid < off) red[tid] = fmaxf(red[tid], red[tid + off]); __syncthreads(); }
  m = red[0]; __syncthreads();
  float e[4], s4 = 0.f;
#pragma unroll
  for (int s = 0; s < 4; ++s) {
    const int j = tid + s * 256;
    e[s] = j < valid ? expf(v[s] - m) : 0.f;
    s4 += e[s];
  }
  red[tid] = s4; __syncthreads();
  for (int off = 128; off; off >>= 1) { if (tid < off) red[tid] += red[tid + off]; __syncthreads(); }
  const float inv = 1.f / red[0];
#pragma unroll
  for (int s = 0; s < 4; ++s) row[tid + s * 256] = __float2bfloat16(e[s] * inv);
}

// ================= PV split-K reduce (all b): av = bf16(t0 + t1), flat 2M elems =================
__global__ __launch_bounds__(256) void pvred_kernel(const float* __restrict__ t, bf16* __restrict__ av_b)
{
  const long i = ((long)blockIdx.x * 256 + threadIdx.x) * 4;   // over 2048*1024
  const float4 a = *(const float4*)(t + i);
  const float4 b = *(const float4*)(t + 2097152 + i);
  av_b[i]     = __float2bfloat16(a.x + b.x);
  av_b[i + 1] = __float2bfloat16(a.y + b.y);
  av_b[i + 2] = __float2bfloat16(a.z + b.z);
  av_b[i + 3] = __float2bfloat16(a.w + b.w);
}

// ================= h = LayerNorm(h + x0 + x1), dual write fp32 h + bf16 cat(upper) =================
__global__ __launch_bounds__(256) void add_ln_kernel(
    float* __restrict__ h,
    const float* __restrict__ x0, const float* __restrict__ x1,
    const float* __restrict__ g, const float* __restrict__ bb, bf16* __restrict__ cat)
{
  float* hr = h + (long)blockIdx.x * DM;
  const long o = (long)blockIdx.x * DM;
  bf16* cr = cat + (long)(2048 + blockIdx.x) * DM;
  const int tid = threadIdx.x;
  __shared__ float red[256];
  float v0 = hr[tid]       + x0[o + tid]       + x1[o + tid];
  float v1 = hr[tid + 256] + x0[o + tid + 256] + x1[o + tid + 256];
  float v2 = hr[tid + 512] + x0[o + tid + 512] + x1[o + tid + 512];
  float v3 = hr[tid + 768] + x0[o + tid + 768] + x1[o + tid + 768];
  red[tid] = v0 + v1 + v2 + v3; __syncthreads();
  for (int off = 128; off; off >>= 1) { if (tid < off) red[tid] += red[tid + off]; __syncthreads(); }
  const float mean = red[0] * (1.f / DM); __syncthreads();
  const float d0 = v0 - mean, d1 = v1 - mean, d2 = v2 - mean, d3 = v3 - mean;
  red[tid] = d0 * d0 + d1 * d1 + d2 * d2 + d3 * d3; __syncthreads();
  for (int off = 128; off; off >>= 1) { if (tid < off) red[tid] += red[tid + off]; __syncthreads(); }
  const float inv = rsqrtf(red[0] * (1.f / DM) + 1e-5f);
  const float o0 = d0 * inv * g[tid]       + bb[tid];
  const float o1 = d1 * inv * g[tid + 256] + bb[tid + 256];
  const float o2 = d2 * inv * g[tid + 512] + bb[tid + 512];
  const float o3 = d3 * inv * g[tid + 768] + bb[tid + 768];
  hr[tid]       = o0;  cr[tid]       = __float2bfloat16(o0);
  hr[tid + 256] = o1;  cr[tid + 256] = __float2bfloat16(o1);
  hr[tid + 512] = o2;  cr[tid + 512] = __float2bfloat16(o2);
  hr[tid + 768] = o3;  cr[tid + 768] = __float2bfloat16(o3);
}

// ================= (q,b,d) -> (b,q,d) =================
__global__ __launch_bounds__(256) void out_kernel(const float* __restrict__ h, float* __restrict__ out)
{
  const int t = blockIdx.x, q = t >> 2, b = t & 3;
  const float* hr = h + (long)t * DM;
  float* orow = out + ((long)b * QLEN + q) * DM;
  for (int s = 0; s < 4; ++s) orow[threadIdx.x + 256 * s] = hr[threadIdx.x + 256 * s];
}

extern "C" void kernel_launch(void* const* d_in, const int* in_sizes, int n_in,
                              void* d_out, int out_size, void* d_ws, size_t ws_size,
                              hipStream_t stream)
{
  const int*   ids  = (const int*)d_in[0];
  const float* mems = (const float*)d_in[1];
  const float* e0 = (const float*)d_in[2]; const float* p0 = (const float*)d_in[3];
  const float* e1 = (const float*)d_in[4]; const float* p1 = (const float*)d_in[5];
  const float* e2 = (const float*)d_in[6]; const float* p2 = (const float*)d_in[7];
  const float* e3 = (const float*)d_in[8]; const float* p3 = (const float*)d_in[9];
  const float* qkvw = (const float*)d_in[10];
  const float* rnet = (const float*)d_in[11];
  const float* ow   = (const float*)d_in[12];
  const float* rwb  = (const float*)d_in[13];
  const float* rrb  = (const float*)d_in[14];
  const float* ln1g = (const float*)d_in[15];
  const float* ln1b = (const float*)d_in[16];
  const float* fw1  = (const float*)d_in[17];
  const float* fb1  = (const float*)d_in[18];
  const float* fw2  = (const float*)d_in[19];
  const float* fb2  = (const float*)d_in[20];
  const float* ln2g = (const float*)d_in[21];
  const float* ln2b = (const float*)d_in[22];
  float* out = (float*)d_out;

  // -------- workspace layout (bytes), total ~359 MB --------
  char* p = (char*)d_ws;
  float* h    = (float*)p;            p += (size_t)2048 * 1024 * 4;       // 8 MB
  bf16*  cat0 = (bf16*)p;             p += (size_t)5 * 4096 * 1024 * 2;   // 40 MB (cats[0..4])
  bf16*  pe   = (bf16*)p;             p += (size_t)1024 * 1024 * 2;       // 2 MB
  bf16*  rkb  = (bf16*)p;             p += (size_t)4 * 1024 * 1024 * 2;   // 8 MB (all layers)
  bf16*  wh   = (bf16*)p;             p += (size_t)4096 * 3072 * 2;       // 24 MB
  bf16*  vt   = (bf16*)p;             p += (size_t)64 * 64 * 1024 * 2;    // 8 MB
  bf16*  qkvT = (bf16*)p;             p += (size_t)4 * 3072 * 1024 * 2;   // 24 MB
  bf16*  rnT  = (bf16*)p;             p += (size_t)4 * 1024 * 1024 * 2;   // 8 MB
  bf16*  oT   = (bf16*)p;             p += (size_t)4 * 1024 * 1024 * 2;   // 8 MB
  bf16*  f1T  = (bf16*)p;             p += (size_t)4 * 4096 * 1024 * 2;   // 32 MB
  bf16*  f2T  = (bf16*)p;             p += (size_t)4 * 4096 * 1024 * 2;   // 32 MB
  // 64 MB region A: sc (attention) / mid (FFN) / partE (embed, 16 MB fp32)
  bf16*  sc   = (bf16*)p;
  bf16*  mid  = (bf16*)p;
  float* partE= (float*)p;
  p += (size_t)4 * 16 * 512 * 1024 * 2;                                   // 64 MB
  // 64 MB region B: bdr (attention) / Aemb+projT (embed) / partP (proj & ffn2 partials, 16 MB fp32)
  bf16*  bdr  = (bf16*)p;
  bf16*  Aemb = (bf16*)p;
  bf16*  projT= (bf16*)(p + (size_t)2048 * KEMB * 2);
  float* partP= (float*)p;
  p += (size_t)4 * 16 * 512 * 1024 * 2;                                   // 64 MB
  bf16*  av   = (bf16*)p;             p += (size_t)2048 * 1024 * 2;       // 4 MB
  float* tmp  = (float*)p;            p += (size_t)2 * 2048 * 1024 * 4;   // 16 MB (PV partials)
  float* acb  = (float*)p;            p += (size_t)4 * 16 * 1024 * 4;     // 256 KB
  float* bcb  = (float*)p;            p += (size_t)4 * 16 * 1024 * 4;     // 256 KB (all layers)

  // -------- upfront: embedding, pos-emb, mems conversion, ALL weight transposes --------
  embA_kernel<<<2048, 256, 0, stream>>>(ids, e0, e1, e2, e3, Aemb);
  projT_kernel<<<dim3(KEMB / 32, 32), 256, 0, stream>>>(p0, p1, p2, p3, projT);
  gemm_bf16<128, 64><<<dim3(16, 16, 2), 256, 0, stream>>>(
      Aemb, 0, 0, KEMB, projT, 0, 0, KEMB, partE, 0, 0, 1024,
      KEMB / 2, 32.f, nullptr, 0, 0, 0, 1, 2, 2097152);
  embsum_kernel<<<2048, 256, 0, stream>>>(partE, h, cat0);
  posemb_kernel<<<1024, 256, 0, stream>>>(pe);
  memsconv_kernel<<<8192, 256, 0, stream>>>(mems, cat0);

  wtrans_kernel<<<dim3(96, 32, 4), 256, 0, stream>>>(qkvw, qkvT, DM, 3072);
  wtrans_kernel<<<dim3(32, 32, 4), 256, 0, stream>>>(rnet, rnT, DM, DM);
  wtrans_kernel<<<dim3(32, 32, 4), 256, 0, stream>>>(ow, oT, DM, DM);
  wtrans_kernel<<<dim3(128, 32, 4), 256, 0, stream>>>(fw1, f1T, DM, DI);
  wtrans_kernel<<<dim3(32, 128, 4), 256, 0, stream>>>(fw2, f2T, DI, DM);

  // rk = pos_emb @ r_net_w for ALL layers (z = layer)
  gemm_bf16<128, 128><<<dim3(8, 8, 4), 256, 0, stream>>>(
      pe, 0, 0, 1024, rnT, 1048576, 0, 1024, rkb, 1048576, 0, 1024,
      1024, 1.f, nullptr, 0, 0, 1, 1, 1, 0);
  bcb_kernel<<<256, 256, 0, stream>>>(rkb, rrb, bcb);

  for (int l = 0; l < NL; ++l) {
    bf16* catl = cat0 + (size_t)l * 4194304;
    // w_heads = cat @ qkv_w  -> wh (bf16, 4096 x 3072)
    gemm_bf16<128, 128><<<dim3(24, 32, 1), 256, 0, stream>>>(
        catl, 0, 0, 1024, qkvT + (size_t)l * 3145728, 0, 0, 1024, wh, 0, 0, 3072,
        1024, 1.f, nullptr, 0, 0, 1, 1, 1, 0);

    vt_kernel<<<dim3(16, 64), 256, 0, stream>>>(wh, vt);
    acb_kernel<<<256, 256, 0, stream>>>(wh, rwb + l * NH * DH, acb);

    // AC: sc = 0.125*(Q.K^T + rwb.K^T), all (b,n) in one launch (z = b*16+n)
    gemm_bf16<128, 128><<<dim3(8, 4, 64), 256, 0, stream>>>(
        wh + (size_t)2048 * 3072, 3072, 64, 12288,
        wh + DM, 3072, 64, 12288,
        sc, (long)16 * 512 * 1024, (long)512 * 1024, 1024,
        64, 0.125f, acb, 16 * 1024, 1024, 1, 16, 1, 0);
    // BD raw: bdr = 0.125*(Q.rk^T + rrb.rk^T), shift applied in softmax
    gemm_bf16<128, 128><<<dim3(8, 4, 64), 256, 0, stream>>>(
        wh + (size_t)2048 * 3072, 3072, 64, 12288,
        rkb + (size_t)l * 1048576, 0, 0, 1024,
        bdr, (long)16 * 512 * 1024, (long)512 * 1024, 1024,
        64, 0.125f, bcb + (size_t)l * 16384, 0, 1024, 1, 16, 1, 0);
    softmax_kernel<<<BSZ * NH * QLEN, 256, 0, stream>>>(sc, bdr);
    // attn_vec = probs @ V (V^T supplied), split-K x2, all (b,n): z = ((b*16+n)*2+chunk)
    gemm_bf16<64, 64><<<dim3(1, 8, 128), 256, 0, stream>>>(
        sc, (long)16 * 512 * 1024, (long)512 * 1024, 1024,
        vt, (long)16 * 64 * 1024, (long)64 * 1024, 1024,
        tmp, 1024, 64, 4096,
        512, 1.f, nullptr, 0, 0, 0, 16, 2, (long)2048 * 1024);
    pvred_kernel<<<2048, 256, 0, stream>>>(tmp, av);

    // attn_out = av @ o_w (split-K x2, fp32 partials into partP), summed in add_ln
    gemm_bf16<128, 64><<<dim3(16, 16, 2), 256, 0, stream>>>(
        av, 0, 0, 1024, oT + (size_t)l * 1048576, 0, 0, 1024, partP, 0, 0, 1024,
        512, 1.f, nullptr, 0, 0, 0, 1, 2, 2097152);
    add_ln_kernel<<<2048, 256, 0, stream>>>(h, partP, partP + 2097152,
                                            ln1g + l * DM, ln1b + l * DM, catl);

    // FFN (mid lives in sc region; partials in partP region — both dead now)
    gemm_bf16<128, 128><<<dim3(32, 16, 1), 256, 0, stream>>>(
        catl + (size_t)2048 * 1024, 0, 0, 1024, f1T + (size_t)l * 4194304, 0, 0, 1024,
        mid, 0, 0, 4096, 1024, 1.f, fb1 + (size_t)l * DI, 0, 0, 1 | 4, 1, 1, 0);
    gemm_bf16<128, 64><<<dim3(16, 16, 2), 256, 0, stream>>>(
        mid, 0, 0, 4096, f2T + (size_t)l * 4194304, 0, 0, 4096, partP, 0, 0, 1024,
        2048, 1.f, fb2 + (size_t)l * DM, 0, 0, 0, 1, 2, 2097152);
    add_ln_kernel<<<2048, 256, 0, stream>>>(h, partP, partP + 2097152,
                                            ln2g + l * DM, ln2b + l * DM,
                                            cat0 + (size_t)(l + 1) * 4194304);
  }

  out_kernel<<<2048, 256, 0, stream>>>(h, out);
}